// Round 11
// baseline (14424.294 us; speedup 1.0000x reference)
//
#include <hip/hip_runtime.h>

#define B_ 16
#define T_ 1024
#define D_ 128
#define H_ 1024
#define O_ 64
#define ALPHA_ 0.1f
#define LEAK_ 0.9f
#define GRID_SCAN 512    // 256 layer-0 engine blocks + 256 layer-1 engine blocks

typedef float f32x4 __attribute__((ext_vector_type(4)));

// ---------------------------------------------------------------------------
// Kernel 1: P0[b][t][j] = ALPHA * (x[b,t,:] . W_in0[j,:] + b0[j])
// written INTO the states0 region of d_out. The scan reads P0 at (b,t,j) and
// overwrites the same address with tanh(v0) -> no extra buffer needed.
// ---------------------------------------------------------------------------
__global__ __launch_bounds__(256)
void p0_kernel(const float* __restrict__ X, const float* __restrict__ Win0,
               const float* __restrict__ b0, float* __restrict__ P)
{
    __shared__ float Xs[64][68];
    __shared__ float Ws[64][68];
    const int r0 = blockIdx.x * 64;
    const int j0 = blockIdx.y * 64;
    const int tid = threadIdx.x;
    const int ty = tid >> 4, tx = tid & 15;
    float acc[4][4] = {};

    for (int kc = 0; kc < D_; kc += 64) {
        for (int i = tid; i < 64 * 16; i += 256) {   // 64 rows x 16 float4
            int row = i >> 4, c = i & 15;
            *(float4*)&Xs[row][c * 4] =
                *(const float4*)&X[(size_t)(r0 + row) * D_ + kc + c * 4];
            *(float4*)&Ws[row][c * 4] =
                *(const float4*)&Win0[(size_t)(j0 + row) * D_ + kc + c * 4];
        }
        __syncthreads();
        #pragma unroll 4
        for (int k = 0; k < 64; k += 4) {
            float4 xr[4], wv[4];
            #pragma unroll
            for (int i = 0; i < 4; ++i) {
                xr[i] = *(const float4*)&Xs[ty * 4 + i][k];
                wv[i] = *(const float4*)&Ws[tx * 4 + i][k];
            }
            #pragma unroll
            for (int i = 0; i < 4; ++i)
                #pragma unroll
                for (int j = 0; j < 4; ++j) {
                    acc[i][j] = fmaf(xr[i].x, wv[j].x, acc[i][j]);
                    acc[i][j] = fmaf(xr[i].y, wv[j].y, acc[i][j]);
                    acc[i][j] = fmaf(xr[i].z, wv[j].z, acc[i][j]);
                    acc[i][j] = fmaf(xr[i].w, wv[j].w, acc[i][j]);
                }
        }
        __syncthreads();
    }
    #pragma unroll
    for (int i = 0; i < 4; ++i) {
        size_t r = (size_t)(r0 + ty * 4 + i);
        #pragma unroll
        for (int j = 0; j < 4; ++j) {
            int jj = j0 + tx * 4 + j;
            P[r * H_ + jj] = ALPHA_ * (acc[i][j] + b0[jj]);
        }
    }
}

// ---------------------------------------------------------------------------
// Kernel 2: fused 2-layer scan — BLOCK-SPECIALIZED DUAL PIPELINE (round 11,
// hardened resubmit of round 10).
//
// Grid 512: blk 0..255 = layer-0 engines (wr0 recurrence, flag0); blk
// 256..511 = layer-1 engines (wi1 + wr1, flag1; consumes flag0). Each
// engine is an independent R9-style loop; the two serial recurrences pay
// their polls/acks/tails CONCURRENTLY instead of serially in one body.
//
// Hardening vs R10: layer-1 engine runs its two load batches SEQUENTIALLY
// (A-batch: load 16, counted-FMA to done; then C-batch: load 16, counted-
// FMA to done). Peak live VGPR ~224 < 256 => no scratch spills inside the
// load->VMWAIT windows (spill ops count in vmcnt and would corrupt the
// counted waits — R9's VGPR_Count=180 < 192 weight regs proved spills
// happen). Costs one exposed C-load latency per iter (~L2 hit).
//
// Deadlock safety: layer-0 blocks never wait on layer-1; in-order dispatch
// => they complete and drain even at 1 block/CU. At the target 2 blocks/CU
// (__launch_bounds__(256,2), LDS 1KB) all 512 are co-resident.
//
// Coherence (R7/R8/R9-HW-proven): state writes = agent-scope relaxed
// atomic stores (sc1 write-through; L2 never dirty); consumer reads =
// plain cached loads (line first cached strictly after its LLC write;
// pval is sc1-bypass); flag publish = relaxed sc1 store after wave-local
// VMWAIT(0) ack; no fences/invalidates anywhere.
//
// LDS red safety WITHOUT trailing barrier: the next POLL includes the
// block's OWN flag, published only after the tail's red reads.
// ---------------------------------------------------------------------------
#define LDX4(dst, p) \
    asm volatile("global_load_dwordx4 %0, %1, off" : "=v"(dst) : "v"(p))
#define LDSC(dst, p) \
    asm volatile("global_load_dword %0, %1, off sc0 sc1" : "=v"(dst) : "v"(p))
#define VMWAIT(n) asm volatile("s_waitcnt vmcnt(" #n ")" ::: "memory")
#define SB0 __builtin_amdgcn_sched_barrier(0)

// wave-coalesced polls: lane L watches dense flag word L; __all exit.
#define POLL1F(pa_, tgtv) do {                                             \
    for (;;) {                                                             \
        unsigned va_;                                                      \
        LDSC(va_, (pa_));                                                  \
        VMWAIT(0);                                                         \
        if (__all((int)(va_ >= (tgtv)))) break;                            \
        __builtin_amdgcn_s_sleep(1);                                       \
    }                                                                      \
    SB0;                                                                   \
} while (0)

#define POLL2F(pa_, pb_, tgtv) do {                                        \
    for (;;) {                                                             \
        unsigned va_, vb_;                                                 \
        LDSC(va_, (pa_));                                                  \
        LDSC(vb_, (pb_));                                                  \
        VMWAIT(0);                                                         \
        if (__all((int)((va_ >= (tgtv)) & (vb_ >= (tgtv))))) break;        \
        __builtin_amdgcn_s_sleep(1);                                       \
    }                                                                      \
    SB0;                                                                   \
} while (0)

// acc[(r)*4+j] += Ar[m][c] * W[j][m*4+c]
#define FMA_G(Ar, r, W) do {                                               \
    _Pragma("unroll")                                                      \
    for (int m_ = 0; m_ < 4; ++m_)                                         \
        _Pragma("unroll")                                                  \
        for (int c_ = 0; c_ < 4; ++c_) {                                   \
            const int kk_ = m_ * 4 + c_;                                   \
            const float x_ = Ar[m_][c_];                                   \
            _Pragma("unroll")                                              \
            for (int j_ = 0; j_ < 4; ++j_)                                 \
                acc[(r)*4+j_] = fmaf(x_, W[j_][kk_], acc[(r)*4+j_]);       \
        }                                                                  \
} while (0)

#define LOAD_ROWS(Rv, base) do {                                           \
    LDX4(Rv##0[0], (base));              LDX4(Rv##0[1], (base) + 4);       \
    LDX4(Rv##0[2], (base) + 8);          LDX4(Rv##0[3], (base) + 12);      \
    LDX4(Rv##1[0], (base) + BT);         LDX4(Rv##1[1], (base) + BT + 4);  \
    LDX4(Rv##1[2], (base) + BT + 8);     LDX4(Rv##1[3], (base) + BT + 12); \
    LDX4(Rv##2[0], (base) + 2*BT);       LDX4(Rv##2[1], (base) + 2*BT + 4);\
    LDX4(Rv##2[2], (base) + 2*BT + 8);   LDX4(Rv##2[3], (base) + 2*BT + 12);\
    LDX4(Rv##3[0], (base) + 3*BT);       LDX4(Rv##3[1], (base) + 3*BT + 4);\
    LDX4(Rv##3[2], (base) + 3*BT + 8);   LDX4(Rv##3[3], (base) + 3*BT + 12);\
} while (0)

__global__ __launch_bounds__(256, 2)
void scan_kernel(const float* __restrict__ Wr0,
                 const float* __restrict__ Wi1,
                 const float* __restrict__ Wr1,
                 const float* __restrict__ b1,
                 float* __restrict__ states0,   // pre-filled with P0
                 float* __restrict__ states1,
                 unsigned int* __restrict__ flags)
{
    const int tid   = threadIdx.x;
    const int blk   = blockIdx.x;
    const int eng   = blk >> 8;              // 0: layer-0 engine, 1: layer-1
    const int inner = blk & 255;
    // XCD-aware: bg-domain d -> XCDs {2d,2d+1}; blk and blk+256 same XCD
    const int xcd  = inner & 7;
    const int slot = inner >> 3;
    const int bg   = xcd >> 1;               // 4 batch-groups of 4
    const int jg   = slot * 2 + (xcd & 1);   // 64 j-groups of 16
    const int lane = tid & 63;
    const int w    = tid >> 6;
    const int jq   = lane & 3;
    const int kl   = lane >> 2;
    const int ks   = w * 16 + kl;            // 0..63
    const int k0   = ks << 4;
    const int jbase = jg * 16 + jq * 4;
    const size_t BT = (size_t)T_ * H_;

    // ---- owners: lanes 0..63 (wave 0) own this engine's 64 outputs ----
    const int o      = tid & 63;
    const int b_loc  = o >> 4, j_loc = o & 15;
    const int gb     = bg * 4 + b_loc;
    const int gj     = jg * 16 + j_loc;
    const int otile  = j_loc >> 2;
    const int oa     = b_loc * 4 + (j_loc & 3);

    __shared__ float red[4][4][16];          // [wave][jq][acc]

    unsigned* flag0 = flags;                 // dense flag0[bg*64 + jg]
    unsigned* flag1 = flags + 256;
    const unsigned* pf0 = flag0 + bg * 64 + lane;
    const unsigned* pf1 = flag1 + bg * 64 + lane;

    if (eng == 0) {
        // =================== LAYER-0 ENGINE (wr0, flag0) ===================
        float wr0[4][16];
        #pragma unroll
        for (int j = 0; j < 4; ++j) {
            const float* p0 = Wr0 + (size_t)(jbase + j) * H_ + k0;
            #pragma unroll
            for (int m = 0; m < 4; ++m)
                *(float4*)&wr0[j][m * 4] = ((const float4*)p0)[m];
        }
        unsigned* myf0 = flag0 + bg * 64 + jg;
        float v0 = 0.f;

        // prologue (t = 0): fr0[0] = tanh(P0[b][0][j])
        if (tid < 64) {
            size_t oidx = (size_t)gb * BT + gj;
            float pv;
            LDSC(pv, states0 + oidx);
            VMWAIT(0); SB0;
            v0 = pv;
            float fr = tanhf(v0);
            __hip_atomic_store(&states0[oidx], fr, __ATOMIC_RELAXED,
                               __HIP_MEMORY_SCOPE_AGENT);
            VMWAIT(0); SB0;               // fr0 store LLC-acked
            if (tid == 0)
                __hip_atomic_store(myf0, 1u, __ATOMIC_RELAXED,
                                   __HIP_MEMORY_SCOPE_AGENT);
        }

        for (int it = 1; it < T_; ++it) {
            POLL1F(pf0, (unsigned)it);    // fr0[it-1] ready (all 64 blocks)

            float acc[16];
            #pragma unroll
            for (int a = 0; a < 16; ++a) acc[a] = 0.f;

            const float* sa = states0 + (size_t)(bg * 4) * BT
                            + (size_t)(it - 1) * H_ + k0;
            f32x4 A0[4], A1[4], A2[4], A3[4];
            LOAD_ROWS(A, sa);
            // pval (sc1 bypass), wave0 only, issued last (counts stay valid)
            float pval = 0.f;
            size_t oidx0 = 0;
            if (tid < 64) {
                oidx0 = (size_t)gb * BT + (size_t)it * H_ + gj;
                LDSC(pval, states0 + oidx0);
            }
            VMWAIT(12); SB0;  FMA_G(A0, 0, wr0);
            VMWAIT(8);  SB0;  FMA_G(A1, 1, wr0);
            VMWAIT(4);  SB0;  FMA_G(A2, 2, wr0);
            VMWAIT(0);  SB0;  FMA_G(A3, 3, wr0);   // also drains pval

            #pragma unroll
            for (int mask = 4; mask < 64; mask <<= 1)
                #pragma unroll
                for (int a = 0; a < 16; ++a)
                    acc[a] += __shfl_xor(acc[a], mask);
            if (lane < 4)
                #pragma unroll
                for (int a = 0; a < 16; ++a)
                    red[w][lane][a] = acc[a];
            __syncthreads();

            if (tid < 64) {
                float s = red[0][otile][oa] + red[1][otile][oa]
                        + red[2][otile][oa] + red[3][otile][oa];
                v0 = LEAK_ * v0 + pval + ALPHA_ * s;
                float fr = tanhf(v0);
                __hip_atomic_store(&states0[oidx0], fr, __ATOMIC_RELAXED,
                                   __HIP_MEMORY_SCOPE_AGENT);
                VMWAIT(0); SB0;           // store LLC-acked (wave0-local)
                if (tid == 0)
                    __hip_atomic_store(myf0, (unsigned)(it + 1),
                                       __ATOMIC_RELAXED,
                                       __HIP_MEMORY_SCOPE_AGENT);
            }
            // no trailing barrier: next POLL includes our own flag0.
        }
    } else {
        // =============== LAYER-1 ENGINE (wi1 + wr1, flag1) ================
        float wi1[4][16], wr1[4][16];
        #pragma unroll
        for (int j = 0; j < 4; ++j) {
            const float* p1 = Wi1 + (size_t)(jbase + j) * H_ + k0;
            const float* p2 = Wr1 + (size_t)(jbase + j) * H_ + k0;
            #pragma unroll
            for (int m = 0; m < 4; ++m) {
                *(float4*)&wi1[j][m * 4] = ((const float4*)p1)[m];
                *(float4*)&wr1[j][m * 4] = ((const float4*)p2)[m];
            }
        }
        unsigned* myf1 = flag1 + bg * 64 + jg;
        float v1 = 0.f;
        const float b1v = (tid < 64) ? b1[gj] : 0.f;

        for (int it = 1; it <= T_; ++it) {
            const unsigned tgt = (unsigned)it;
            // need fr0[it-1] (flag0>=it) and, for it>=2, fr1[it-2] (flag1>=it)
            if (it >= 2) POLL2F(pf0, pf1, tgt);
            else         POLL1F(pf0, tgt);

            float acc[16];
            #pragma unroll
            for (int a = 0; a < 16; ++a) acc[a] = 0.f;

            // ---- A batch (fr0[it-1] rows), fully consumed before C ----
            {
                const float* sa = states0 + (size_t)(bg * 4) * BT
                                + (size_t)(it - 1) * H_ + k0;
                f32x4 A0[4], A1[4], A2[4], A3[4];
                LOAD_ROWS(A, sa);
                VMWAIT(12); SB0;  FMA_G(A0, 0, wi1);
                VMWAIT(8);  SB0;  FMA_G(A1, 1, wi1);
                VMWAIT(4);  SB0;  FMA_G(A2, 2, wi1);
                VMWAIT(0);  SB0;  FMA_G(A3, 3, wi1);
            }
            // ---- C batch (fr1[it-2] rows), sequential (low VGPR peak) ----
            if (it >= 2) {
                const float* sb = states1 + (size_t)(bg * 4) * BT
                                + (size_t)(it - 2) * H_ + k0;
                f32x4 C0[4], C1[4], C2[4], C3[4];
                LOAD_ROWS(C, sb);
                VMWAIT(12); SB0;  FMA_G(C0, 0, wr1);
                VMWAIT(8);  SB0;  FMA_G(C1, 1, wr1);
                VMWAIT(4);  SB0;  FMA_G(C2, 2, wr1);
                VMWAIT(0);  SB0;  FMA_G(C3, 3, wr1);
            }

            #pragma unroll
            for (int mask = 4; mask < 64; mask <<= 1)
                #pragma unroll
                for (int a = 0; a < 16; ++a)
                    acc[a] += __shfl_xor(acc[a], mask);
            if (lane < 4)
                #pragma unroll
                for (int a = 0; a < 16; ++a)
                    red[w][lane][a] = acc[a];
            __syncthreads();

            if (tid < 64) {
                float s = red[0][otile][oa] + red[1][otile][oa]
                        + red[2][otile][oa] + red[3][otile][oa];
                v1 = LEAK_ * v1 + ALPHA_ * (s + b1v);
                float fr = tanhf(v1);
                __hip_atomic_store(&states1[(size_t)gb * BT
                                            + (size_t)(it - 1) * H_ + gj],
                                   fr, __ATOMIC_RELAXED,
                                   __HIP_MEMORY_SCOPE_AGENT);
                VMWAIT(0); SB0;           // store LLC-acked (wave0-local)
                if (tid == 0)
                    __hip_atomic_store(myf1, (unsigned)(it + 1),
                                       __ATOMIC_RELAXED,
                                       __HIP_MEMORY_SCOPE_AGENT);
            }
            // no trailing barrier: next POLL includes our own flag1.
        }
    }
}

// ---------------------------------------------------------------------------
// Kernel 3: out[r][o] = states1[r,:] . W_out[o,:] + b_out[o],  r = b*T+t
// ---------------------------------------------------------------------------
__global__ __launch_bounds__(256)
void out_kernel(const float* __restrict__ S1, const float* __restrict__ Wout,
                const float* __restrict__ bout, float* __restrict__ Out)
{
    __shared__ float Ss[64][36];
    __shared__ float Ws[64][36];
    const int r0 = blockIdx.x * 64;
    const int tid = threadIdx.x;
    const int ty = tid >> 4, tx = tid & 15;
    float acc[4][4] = {};

    for (int kc = 0; kc < H_; kc += 32) {
        for (int i = tid; i < 64 * 8; i += 256) {   // 64 rows x 8 float4
            int row = i >> 3, c = i & 7;
            *(float4*)&Ss[row][c * 4] =
                *(const float4*)&S1[(size_t)(r0 + row) * H_ + kc + c * 4];
            *(float4*)&Ws[row][c * 4] =
                *(const float4*)&Wout[(size_t)row * H_ + kc + c * 4];
        }
        __syncthreads();
        #pragma unroll 2
        for (int k = 0; k < 32; k += 4) {
            float4 xr[4], wv[4];
            #pragma unroll
            for (int i = 0; i < 4; ++i) {
                xr[i] = *(const float4*)&Ss[ty * 4 + i][k];
                wv[i] = *(const float4*)&Ws[tx * 4 + i][k];
            }
            #pragma unroll
            for (int i = 0; i < 4; ++i)
                #pragma unroll
                for (int j = 0; j < 4; ++j) {
                    acc[i][j] = fmaf(xr[i].x, wv[j].x, acc[i][j]);
                    acc[i][j] = fmaf(xr[i].y, wv[j].y, acc[i][j]);
                    acc[i][j] = fmaf(xr[i].z, wv[j].z, acc[i][j]);
                    acc[i][j] = fmaf(xr[i].w, wv[j].w, acc[i][j]);
                }
        }
        __syncthreads();
    }
    #pragma unroll
    for (int i = 0; i < 4; ++i) {
        size_t r = (size_t)(r0 + ty * 4 + i);
        #pragma unroll
        for (int j = 0; j < 4; ++j) {
            int oo = tx * 4 + j;
            Out[r * O_ + oo] = acc[i][j] + bout[oo];
        }
    }
}

// ---------------------------------------------------------------------------
extern "C" void kernel_launch(void* const* d_in, const int* in_sizes, int n_in,
                              void* d_out, int out_size, void* d_ws, size_t ws_size,
                              hipStream_t stream)
{
    (void)in_sizes; (void)n_in; (void)out_size; (void)ws_size;

    const float* x    = (const float*)d_in[0];
    const float* Win0 = (const float*)d_in[1];
    const float* Wr0  = (const float*)d_in[2];
    const float* b0   = (const float*)d_in[3];
    const float* Wi1  = (const float*)d_in[4];
    const float* Wr1  = (const float*)d_in[5];
    const float* b1   = (const float*)d_in[6];
    const float* Wout = (const float*)d_in[7];
    const float* bout = (const float*)d_in[8];

    float* out     = (float*)d_out;
    float* states0 = out + (size_t)B_ * T_ * O_;
    float* states1 = states0 + (size_t)B_ * T_ * H_;

    unsigned* flags = (unsigned*)d_ws;   // dense: flag0[256] ++ flag1[256]

    // zero flag words (ws is poisoned 0xAA before every call)
    hipMemsetAsync(d_ws, 0, 512 * sizeof(unsigned), stream);

    // P0 -> states0 region
    p0_kernel<<<dim3(B_ * T_ / 64, H_ / 64), 256, 0, stream>>>(x, Win0, b0, states0);

    // fused scan (dual-pipeline)
    scan_kernel<<<dim3(GRID_SCAN), dim3(256), 0, stream>>>(
        Wr0, Wi1, Wr1, b1, states0, states1, flags);

    // readout
    out_kernel<<<dim3(B_ * T_ / 64), 256, 0, stream>>>(states1, Wout, bout, out);
}